// Round 8
// baseline (5108.500 us; speedup 1.0000x reference)
//
#include <hip/hip_runtime.h>

typedef unsigned int u32;
typedef __fp16 f16;
typedef __fp16 h2 __attribute__((ext_vector_type(2)));
typedef __fp16 h4 __attribute__((ext_vector_type(4)));
typedef __fp16 h8 __attribute__((ext_vector_type(8)));
typedef float f32x2v __attribute__((ext_vector_type(2)));
typedef float f32x4v __attribute__((ext_vector_type(4)));
typedef float f32x16v __attribute__((ext_vector_type(16)));
typedef u32 u32x2v __attribute__((ext_vector_type(2)));
typedef u32 u32x4v __attribute__((ext_vector_type(4)));

static constexpr int BB = 64;     // batch
static constexpr int TT = 1024;   // seq len
static constexpr int HH = 256;    // hidden
static constexpr int GG = 768;    // 3*H
static constexpr size_t GI_BYTES = (size_t)BB * TT * GG * 2;  // f16 gi buffer

__device__ __forceinline__ u32 pk2(float a, float b) {
  h2 r = __builtin_amdgcn_cvt_pkrtz(a, b);
  return __builtin_bit_cast(u32, r);
}
__device__ __forceinline__ float sigf(float x) { return 1.f / (1.f + __expf(-x)); }
__device__ __forceinline__ float tanhf2(float x) {
  float e = __expf(2.f * x);
  return 1.f - 2.f / (e + 1.f);
}

// ---------------------------------------------------------------------------
// Phase 0: prepack W_hh (768x256 f32) into per-lane MFMA A-fragment streams.
// recur: 4 waves, wave w owns tiles m = G*16 + 4w + i (G=0..2 gates, i=0..3),
// frag f = (G*4+i)*8 + ks.  A-frag lane l: row = 16m + (l&15),
// k = 32ks + 8(l>>4) + 2e2 (+1).   Wa[((w*64+l)*96 + f)*4 + e2].
// (Same A/B/D lane conventions as the round-7 kernel, which passed checks.)
// ---------------------------------------------------------------------------
__global__ void prepack_wa(const float* __restrict__ Whh, u32* __restrict__ Wa) {
  int id = blockIdx.x * 256 + threadIdx.x;  // [0, 98304)
  int e2 = id & 3;
  int f = (id >> 2) % 96;
  int lg = id / 384;                         // w*64 + l
  int w = lg >> 6, l = lg & 63;
  int G = f >> 5, rem = f & 31, i = rem >> 3, ks = rem & 7;
  int m = G * 16 + 4 * w + i;
  int row = 16 * m + (l & 15);
  int k = 32 * ks + 8 * (l >> 4) + 2 * e2;
  const float* p = Whh + (size_t)row * HH + k;
  Wa[id] = pk2(p[0], p[1]);
}

// ---------------------------------------------------------------------------
// Phase 1: gi = x @ W_ih^T + b_ih (+ b_hh folded for r,z gates), stored f16.
// ---------------------------------------------------------------------------
__device__ __forceinline__ f32x16v zero16() {
  f32x16v z;
#pragma unroll
  for (int i = 0; i < 16; ++i) z[i] = 0.f;
  return z;
}

__global__ __launch_bounds__(256, 2) void gemm_gi(
    const float* __restrict__ x, const float* __restrict__ Wih,
    const float* __restrict__ bih, const float* __restrict__ bhh,
    f16* __restrict__ gi) {
  __shared__ u32 bl[16384];  // 128 rows x 128 dwords (f16x2) = 64KB
  const int tid = threadIdx.x;
  const int lane = tid & 63;
  const int wv = tid >> 6;
  const int wr = wv >> 1, wc = wv & 1;
  const int l31 = lane & 31, lh = lane >> 5;
  const int m0 = blockIdx.x << 7;

  u32x4v afr[2][16];
#pragma unroll
  for (int fr = 0; fr < 2; ++fr) {
#pragma unroll
    for (int km = 0; km < 16; ++km) {
      int row = m0 + wr * 64 + fr * 32 + l31;
      int k0 = km * 16 + lh * 8;
      const f32x4v* p = (const f32x4v*)(x + (size_t)row * 256 + k0);
      f32x4v u = p[0], v = p[1];
      u32x4v t;
      t.x = pk2(u.x, u.y); t.y = pk2(u.z, u.w);
      t.z = pk2(v.x, v.y); t.w = pk2(v.z, v.w);
      afr[fr][km] = t;
    }
  }

  for (int nt = 0; nt < 6; ++nt) {
    const int n0 = nt << 7;
#pragma unroll
    for (int it = 0; it < 32; ++it) {
      int flat = it * 256 + tid;
      int r = flat >> 6;
      int q = flat & 63;
      f32x4v f = *(const f32x4v*)(Wih + (size_t)(n0 + r) * 256 + 4 * q);
      u32x2v pw;
      pw.x = pk2(f.x, f.y);
      pw.y = pk2(f.z, f.w);
      int wd = 2 * q;
      *(u32x2v*)&bl[r * 128 + (wd ^ ((r & 15) << 2))] = pw;
    }
    __syncthreads();

    f32x16v acc00 = zero16(), acc01 = zero16(), acc10 = zero16(), acc11 = zero16();
#pragma unroll
    for (int km = 0; km < 16; ++km) {
      int w0 = km * 8 + lh * 4;
      int rc0 = wc * 64 + l31;
      int rc1 = wc * 64 + 32 + l31;
      u32x4v b0 = *(const u32x4v*)&bl[rc0 * 128 + (w0 ^ ((rc0 & 15) << 2))];
      u32x4v b1 = *(const u32x4v*)&bl[rc1 * 128 + (w0 ^ ((rc1 & 15) << 2))];
      h8 a0h = __builtin_bit_cast(h8, afr[0][km]);
      h8 a1h = __builtin_bit_cast(h8, afr[1][km]);
      h8 b0h = __builtin_bit_cast(h8, b0);
      h8 b1h = __builtin_bit_cast(h8, b1);
      acc00 = __builtin_amdgcn_mfma_f32_32x32x16_f16(a0h, b0h, acc00, 0, 0, 0);
      acc10 = __builtin_amdgcn_mfma_f32_32x32x16_f16(a1h, b0h, acc10, 0, 0, 0);
      acc01 = __builtin_amdgcn_mfma_f32_32x32x16_f16(a0h, b1h, acc01, 0, 0, 0);
      acc11 = __builtin_amdgcn_mfma_f32_32x32x16_f16(a1h, b1h, acc11, 0, 0, 0);
    }

#define EPI(ACC, FR, FC)                                                      \
    {                                                                         \
      int gc = n0 + wc * 64 + (FC) * 32 + l31;                                \
      float bias = bih[gc] + (gc < 512 ? bhh[gc] : 0.f);                      \
      _Pragma("unroll")                                                       \
      for (int rg = 0; rg < 16; ++rg) {                                       \
        int gr = m0 + wr * 64 + (FR) * 32 + 4 * lh + (rg & 3) + 8 * (rg >> 2);\
        gi[(size_t)gr * 768 + gc] = (f16)(ACC[rg] + bias);                    \
      }                                                                       \
    }
    EPI(acc00, 0, 0) EPI(acc10, 1, 0) EPI(acc01, 0, 1) EPI(acc11, 1, 1)
#undef EPI
    __syncthreads();
  }
}

// ---------------------------------------------------------------------------
// Phase 2: recurrence via MFMA, weights PURE-VGPR at 1 wave/SIMD.
// 16 blocks x 4 batches, 256 thr (4 waves).  __launch_bounds__(256,1) gives a
// 512-VGPR budget: 96 A-frags (384 VGPR) + 12 acc (48) + working fits.
// Wave w owns tiles {G*16+4w+i} = full r/z/n triples for units [64w,64w+64):
// no cross-lane rebalance.  h f16 in LDS (B-fragment order), double-buffered,
// one barrier per step.  B cols 0..3 = real batches, 4..15 = zero.
// ---------------------------------------------------------------------------
__global__ __launch_bounds__(256, 1) void recur(
    const u32* __restrict__ Wa, const f16* __restrict__ gi,
    const float* __restrict__ states, const float* __restrict__ mask,
    const float* __restrict__ bhh_g, float* __restrict__ out) {
  const int blk = blockIdx.x;          // 0..15
  const int tid = threadIdx.x;         // 0..255
  const int w = tid >> 6, l = tid & 63;
  const int lr = l & 15, g = l >> 4;   // D: col=lr, rows 4g..4g+3
  const int cb = lr & 3;               // clamped batch col
  const bool act = (lr < 4);
  const int bb = blk * 4 + cb;
  const int u0 = 64 * w;               // unit = u0 + 16i + 4g + r

  __shared__ __align__(16) f16 hb[2][4096];  // [ks][kq][col16][e8]
  __shared__ f16 mlds[4096];                 // [t][batch4]
  __shared__ float bnlds[256];               // b_hh n-gate

  // ---- weights: 96 b128 loads, kept in VGPRs ----
  u32x4v wreg[96];
  {
    const u32x4v* wap = (const u32x4v*)Wa + (size_t)(w * 64 + l) * 96;
#pragma unroll
    for (int f = 0; f < 96; ++f) wreg[f] = wap[f];
  }

  // ---- stage mask, n-bias, h0 ----
  for (int idx = tid; idx < 4096; idx += 256) {
    int b4 = idx & 3, tt = idx >> 2;
    mlds[idx] = (f16)mask[(size_t)(blk * 4 + b4) * TT + tt];
  }
  bnlds[tid] = bhh_g[512 + tid];
  for (int idx = tid; idx < 4096; idx += 256) {
    int unit = idx >> 4, col = idx & 15;
    float v = 0.f;
    if (col < 4)
      v = states[(size_t)(blk * 4 + col) * HH + unit] *
          mask[(size_t)(blk * 4 + col) * TT];
    int fa = (unit >> 5) * 512 + ((unit >> 3) & 3) * 128 + col * 8 + (unit & 7);
    hb[0][fa] = (f16)v;
    hb[1][fa] = (f16)v;
  }

  const f16* gib = gi + (size_t)bb * TT * GG;
  float* outb = out + (size_t)bb * TT * HH;
  const int rbase = g * 128 + lr * 8;  // B-frag f16 base (+ks*512)
  int fa_i[4];                         // h-fragment addr per i (this lane's units)
#pragma unroll
  for (int i = 0; i < 4; ++i)
    fa_i[i] = (2 * w + (i >> 1)) * 512 + ((2 * (i & 1) + (g >> 1)) & 3) * 128 +
              cb * 8 + 4 * (g & 1);

  const f32x4v zero4 = {0.f, 0.f, 0.f, 0.f};
  f32x4v nhp[4];
#pragma unroll
  for (int i = 0; i < 4; ++i) nhp[i] = zero4;

  __syncthreads();

#pragma unroll 1
  for (int t = 0; t < TT; ++t) {
    // deferred out-store of step t-1 (ack hides under this step's MFMA phase)
    if (t > 0 && act) {
#pragma unroll
      for (int i = 0; i < 4; ++i)
        *(f32x4v*)(outb + (size_t)(t - 1) * HH + u0 + 16 * i + 4 * g) = nhp[i];
    }
    // gi loads for this step (12 x 8B, consumed at gate phase)
    h4 gv[3][4];
#pragma unroll
    for (int G = 0; G < 3; ++G)
#pragma unroll
      for (int i = 0; i < 4; ++i)
        gv[G][i] = *(const h4*)(gib + (size_t)t * GG + G * 256 + u0 + 16 * i + 4 * g);
    const float mt = (float)mlds[t * 4 + cb];

    // ---- MFMA phase: 12 tiles x 8 K-slices ----
    const u32x4v* bp = (const u32x4v*)&hb[t & 1][rbase];
    f32x4v acc[12];
#pragma unroll
    for (int a = 0; a < 12; ++a) acc[a] = zero4;
    u32x4v bf = bp[0];
#pragma unroll
    for (int ks = 0; ks < 8; ++ks) {
      u32x4v bnx = bp[((ks + 1) & 7) * 64];  // prefetch next K-slice
      h8 bh = __builtin_bit_cast(h8, bf);
#pragma unroll
      for (int a = 0; a < 12; ++a)
        acc[a] = __builtin_amdgcn_mfma_f32_16x16x32_f16(
            __builtin_bit_cast(h8, wreg[a * 8 + ks]), bh, acc[a], 0, 0, 0);
      bf = bnx;
    }

    // ---- gate phase (all lanes compute; only col<4 lanes commit) ----
#pragma unroll
    for (int i = 0; i < 4; ++i) {
      h4 hold4 = *(const h4*)&hb[t & 1][fa_i[i]];
      f32x4v bn4 = *(const f32x4v*)&bnlds[u0 + 16 * i + 4 * g];
      f32x4v nh4, hn4;
#pragma unroll
      for (int r = 0; r < 4; ++r) {
        float hold = (float)hold4[r];
        float rr = sigf((float)gv[0][i][r] + acc[i][r]);
        float zz = sigf((float)gv[1][i][r] + acc[4 + i][r]);
        float nn = tanhf2((float)gv[2][i][r] + rr * (acc[8 + i][r] + bn4[r]));
        float nh = zz * (hold - nn) + nn;      // (1-z)n + z h
        nh4[r] = nh;
        hn4[r] = hold + mt * (nh - hold);      // mask blend
      }
      nhp[i] = nh4;
      if (act) {
        u32x2v hp;
        hp.x = pk2(hn4[0], hn4[1]);
        hp.y = pk2(hn4[2], hn4[3]);
        *(u32x2v*)&hb[(t + 1) & 1][fa_i[i]] = hp;
      }
    }
    __syncthreads();
  }

  if (act) {
#pragma unroll
    for (int i = 0; i < 4; ++i)
      *(f32x4v*)(outb + (size_t)(TT - 1) * HH + u0 + 16 * i + 4 * g) = nhp[i];
    // final state: h after step TT-1 lives in hb[TT&1] = hb[0]
#pragma unroll
    for (int i = 0; i < 4; ++i) {
      h4 hf = *(const h4*)&hb[0][fa_i[i]];
      f32x4v o;
#pragma unroll
      for (int r = 0; r < 4; ++r) o[r] = (float)hf[r];
      *(f32x4v*)(out + (size_t)BB * TT * HH + (size_t)bb * HH + u0 + 16 * i + 4 * g) = o;
    }
  }
}

extern "C" void kernel_launch(void* const* d_in, const int* in_sizes, int n_in,
                              void* d_out, int out_size, void* d_ws, size_t ws_size,
                              hipStream_t stream) {
  const float* x      = (const float*)d_in[0];
  const float* states = (const float*)d_in[1];
  const float* mask   = (const float*)d_in[2];
  const float* W_ih   = (const float*)d_in[3];
  const float* W_hh   = (const float*)d_in[4];
  const float* b_ih   = (const float*)d_in[5];
  const float* b_hh   = (const float*)d_in[6];
  float* out = (float*)d_out;

  char* ws = (char*)d_ws;
  f16* gi = (f16*)ws;
  u32* Wa = (u32*)(ws + GI_BYTES);

  prepack_wa<<<dim3(384), dim3(256), 0, stream>>>(W_hh, Wa);
  gemm_gi<<<dim3(512), dim3(256), 0, stream>>>(x, W_ih, b_ih, b_hh, gi);
  recur<<<dim3(16), dim3(256), 0, stream>>>(Wa, gi, states, mask, b_hh, out);
}

// Round 9
// 3856.815 us; speedup vs baseline: 1.3245x; 1.3245x over previous
//
#include <hip/hip_runtime.h>

typedef unsigned int u32;
typedef __fp16 f16;
typedef __fp16 h2 __attribute__((ext_vector_type(2)));
typedef __fp16 h4 __attribute__((ext_vector_type(4)));
typedef __fp16 h8 __attribute__((ext_vector_type(8)));
typedef float f32x2v __attribute__((ext_vector_type(2)));
typedef float f32x4v __attribute__((ext_vector_type(4)));
typedef float f32x16v __attribute__((ext_vector_type(16)));
typedef u32 u32x2v __attribute__((ext_vector_type(2)));
typedef u32 u32x4v __attribute__((ext_vector_type(4)));

static constexpr int BB = 64;     // batch
static constexpr int TT = 1024;   // seq len
static constexpr int HH = 256;    // hidden
static constexpr int GG = 768;    // 3*H
static constexpr size_t GI_BYTES = (size_t)BB * TT * GG * 2;  // f16 gi buffer

__device__ __forceinline__ u32 pk2(float a, float b) {
  h2 r = __builtin_amdgcn_cvt_pkrtz(a, b);
  return __builtin_bit_cast(u32, r);
}
__device__ __forceinline__ float sigf(float x) { return 1.f / (1.f + __expf(-x)); }
__device__ __forceinline__ float tanhf2(float x) {
  float e = __expf(2.f * x);
  return 1.f - 2.f / (e + 1.f);
}

// ---------------------------------------------------------------------------
// Phase 0: prepack W_hh (768x256 f32) into per-lane MFMA A-fragment streams.
// recur: 4 waves, wave w owns tiles m = G*16 + 4w + i (G=0..2 gates, i=0..3),
// frag f = (G*4+i)*8 + ks.  A-frag lane l: row = 16m + (l&15),
// k = 32ks + 8(l>>4) + 2e2 (+1).   Wa[((w*64+l)*96 + f)*4 + e2].
// (Identical fragment conventions to round-8, which passed correctness.)
// ---------------------------------------------------------------------------
__global__ void prepack_wa(const float* __restrict__ Whh, u32* __restrict__ Wa) {
  int id = blockIdx.x * 256 + threadIdx.x;  // [0, 98304)
  int e2 = id & 3;
  int f = (id >> 2) % 96;
  int lg = id / 384;                         // w*64 + l
  int w = lg >> 6, l = lg & 63;
  int G = f >> 5, rem = f & 31, i = rem >> 3, ks = rem & 7;
  int m = G * 16 + 4 * w + i;
  int row = 16 * m + (l & 15);
  int k = 32 * ks + 8 * (l >> 4) + 2 * e2;
  const float* p = Whh + (size_t)row * HH + k;
  Wa[id] = pk2(p[0], p[1]);
}

// ---------------------------------------------------------------------------
// Phase 1: gi = x @ W_ih^T + b_ih (+ b_hh folded for r,z gates), stored f16.
// ---------------------------------------------------------------------------
__device__ __forceinline__ f32x16v zero16() {
  f32x16v z;
#pragma unroll
  for (int i = 0; i < 16; ++i) z[i] = 0.f;
  return z;
}

__global__ __launch_bounds__(256, 2) void gemm_gi(
    const float* __restrict__ x, const float* __restrict__ Wih,
    const float* __restrict__ bih, const float* __restrict__ bhh,
    f16* __restrict__ gi) {
  __shared__ u32 bl[16384];  // 128 rows x 128 dwords (f16x2) = 64KB
  const int tid = threadIdx.x;
  const int lane = tid & 63;
  const int wv = tid >> 6;
  const int wr = wv >> 1, wc = wv & 1;
  const int l31 = lane & 31, lh = lane >> 5;
  const int m0 = blockIdx.x << 7;

  u32x4v afr[2][16];
#pragma unroll
  for (int fr = 0; fr < 2; ++fr) {
#pragma unroll
    for (int km = 0; km < 16; ++km) {
      int row = m0 + wr * 64 + fr * 32 + l31;
      int k0 = km * 16 + lh * 8;
      const f32x4v* p = (const f32x4v*)(x + (size_t)row * 256 + k0);
      f32x4v u = p[0], v = p[1];
      u32x4v t;
      t.x = pk2(u.x, u.y); t.y = pk2(u.z, u.w);
      t.z = pk2(v.x, v.y); t.w = pk2(v.z, v.w);
      afr[fr][km] = t;
    }
  }

  for (int nt = 0; nt < 6; ++nt) {
    const int n0 = nt << 7;
#pragma unroll
    for (int it = 0; it < 32; ++it) {
      int flat = it * 256 + tid;
      int r = flat >> 6;
      int q = flat & 63;
      f32x4v f = *(const f32x4v*)(Wih + (size_t)(n0 + r) * 256 + 4 * q);
      u32x2v pw;
      pw.x = pk2(f.x, f.y);
      pw.y = pk2(f.z, f.w);
      int wd = 2 * q;
      *(u32x2v*)&bl[r * 128 + (wd ^ ((r & 15) << 2))] = pw;
    }
    __syncthreads();

    f32x16v acc00 = zero16(), acc01 = zero16(), acc10 = zero16(), acc11 = zero16();
#pragma unroll
    for (int km = 0; km < 16; ++km) {
      int w0 = km * 8 + lh * 4;
      int rc0 = wc * 64 + l31;
      int rc1 = wc * 64 + 32 + l31;
      u32x4v b0 = *(const u32x4v*)&bl[rc0 * 128 + (w0 ^ ((rc0 & 15) << 2))];
      u32x4v b1 = *(const u32x4v*)&bl[rc1 * 128 + (w0 ^ ((rc1 & 15) << 2))];
      h8 a0h = __builtin_bit_cast(h8, afr[0][km]);
      h8 a1h = __builtin_bit_cast(h8, afr[1][km]);
      h8 b0h = __builtin_bit_cast(h8, b0);
      h8 b1h = __builtin_bit_cast(h8, b1);
      acc00 = __builtin_amdgcn_mfma_f32_32x32x16_f16(a0h, b0h, acc00, 0, 0, 0);
      acc10 = __builtin_amdgcn_mfma_f32_32x32x16_f16(a1h, b0h, acc10, 0, 0, 0);
      acc01 = __builtin_amdgcn_mfma_f32_32x32x16_f16(a0h, b1h, acc01, 0, 0, 0);
      acc11 = __builtin_amdgcn_mfma_f32_32x32x16_f16(a1h, b1h, acc11, 0, 0, 0);
    }

#define EPI(ACC, FR, FC)                                                      \
    {                                                                         \
      int gc = n0 + wc * 64 + (FC) * 32 + l31;                                \
      float bias = bih[gc] + (gc < 512 ? bhh[gc] : 0.f);                      \
      _Pragma("unroll")                                                       \
      for (int rg = 0; rg < 16; ++rg) {                                       \
        int gr = m0 + wr * 64 + (FR) * 32 + 4 * lh + (rg & 3) + 8 * (rg >> 2);\
        gi[(size_t)gr * 768 + gc] = (f16)(ACC[rg] + bias);                    \
      }                                                                       \
    }
    EPI(acc00, 0, 0) EPI(acc10, 1, 0) EPI(acc01, 0, 1) EPI(acc11, 1, 1)
#undef EPI
    __syncthreads();
  }
}

// ---------------------------------------------------------------------------
// Phase 2: recurrence via MFMA, weights split AGPR(64 frags)+VGPR(32 frags).
// 16 blocks x 4 batches, 256 thr (4 waves, 1/SIMD): unified budget 512/wave =
// 256 V + 256 A.  Gates r,z (8 tiles x 8 ks = 64 frags) live in exactly 256
// AGPRs; gate n (4 tiles = 32 frags = 128 dwords) in VGPRs.  Raw asm MFMA
// with "a"/"v" A-operand so no copies are possible.  h f16 in LDS
// (B-fragment order), double-buffered, one barrier per step.
// ---------------------------------------------------------------------------
#define MFMA_A(ACC, AW, BV) \
  asm("v_mfma_f32_16x16x32_f16 %0, %1, %2, %0" : "+v"(ACC) : "a"(AW), "v"(BV))
#define MFMA_V(ACC, AW, BV) \
  asm("v_mfma_f32_16x16x32_f16 %0, %1, %2, %0" : "+v"(ACC) : "v"(AW), "v"(BV))

__global__ __launch_bounds__(256, 1) void recur(
    const u32* __restrict__ Wa, const f16* __restrict__ gi,
    const float* __restrict__ states, const float* __restrict__ mask,
    const float* __restrict__ bhh_g, float* __restrict__ out) {
  const int blk = blockIdx.x;          // 0..15
  const int tid = threadIdx.x;         // 0..255
  const int w = tid >> 6, l = tid & 63;
  const int lr = l & 15, g = l >> 4;   // D: col=lr, rows 4g..4g+3
  const int cb = lr & 3;               // clamped batch col
  const bool act = (lr < 4);
  const int bb = blk * 4 + cb;
  const int u0 = 64 * w;               // unit = u0 + 16i + 4g + r

  __shared__ __align__(16) f16 hb[2][4096];  // [ks][kq][col16][e8]
  __shared__ f16 mlds[4096];                 // [t][batch4]
  __shared__ float bnlds[256];               // b_hh n-gate

  // ---- weights: 64 frags -> AGPRs (r,z gates), 32 frags -> VGPRs (n gate) ----
  u32x4v wA[64];
  u32x4v wV[32];
  {
    const u32x4v* wap = (const u32x4v*)Wa + (size_t)(w * 64 + l) * 96;
#pragma unroll
    for (int f = 0; f < 64; ++f) wA[f] = wap[f];
#pragma unroll
    for (int f = 0; f < 32; ++f) wV[f] = wap[64 + f];
  }
#pragma unroll
  for (int f = 0; f < 64; ++f) asm volatile("" : "+a"(wA[f]));
#pragma unroll
  for (int f = 0; f < 32; ++f) asm volatile("" : "+v"(wV[f]));

  // ---- stage mask, n-bias, h0 ----
  for (int idx = tid; idx < 4096; idx += 256) {
    int b4 = idx & 3, tt = idx >> 2;
    mlds[idx] = (f16)mask[(size_t)(blk * 4 + b4) * TT + tt];
  }
  bnlds[tid] = bhh_g[512 + tid];
  for (int idx = tid; idx < 4096; idx += 256) {
    int unit = idx >> 4, col = idx & 15;
    float v = 0.f;
    if (col < 4)
      v = states[(size_t)(blk * 4 + col) * HH + unit] *
          mask[(size_t)(blk * 4 + col) * TT];
    int fa = (unit >> 5) * 512 + ((unit >> 3) & 3) * 128 + col * 8 + (unit & 7);
    hb[0][fa] = (f16)v;
    hb[1][fa] = (f16)v;
  }

  const f16* gib = gi + (size_t)bb * TT * GG;
  float* outb = out + (size_t)bb * TT * HH;
  const int rbase = g * 128 + lr * 8;  // B-frag f16 base (+ks*512)
  int fa_i[4];                         // h-fragment addr per i (this lane's units)
#pragma unroll
  for (int i = 0; i < 4; ++i)
    fa_i[i] = (2 * w + (i >> 1)) * 512 + ((2 * (i & 1) + (g >> 1)) & 3) * 128 +
              cb * 8 + 4 * (g & 1);

  const f32x4v zero4 = {0.f, 0.f, 0.f, 0.f};
  f32x4v nhp[4];
#pragma unroll
  for (int i = 0; i < 4; ++i) nhp[i] = zero4;

  __syncthreads();

#pragma unroll 1
  for (int t = 0; t < TT; ++t) {
    // deferred out-store of step t-1 (ack hides under this step's MFMA phase)
    if (t > 0 && act) {
#pragma unroll
      for (int i = 0; i < 4; ++i)
        *(f32x4v*)(outb + (size_t)(t - 1) * HH + u0 + 16 * i + 4 * g) = nhp[i];
    }
    // gi loads for this step (12 x 8B, consumed at gate phase)
    h4 gv[3][4];
#pragma unroll
    for (int G = 0; G < 3; ++G)
#pragma unroll
      for (int i = 0; i < 4; ++i)
        gv[G][i] = *(const h4*)(gib + (size_t)t * GG + G * 256 + u0 + 16 * i + 4 * g);
    const float mt = (float)mlds[t * 4 + cb];

    // ---- MFMA phase: 12 tiles x 8 K-slices ----
    const u32x4v* bp = (const u32x4v*)&hb[t & 1][rbase];
    f32x4v acc[12];
#pragma unroll
    for (int a = 0; a < 12; ++a) acc[a] = zero4;
    u32x4v bf = bp[0];
#pragma unroll
    for (int ks = 0; ks < 8; ++ks) {
      u32x4v bnx = bp[((ks + 1) & 7) * 64];  // prefetch next K-slice
#pragma unroll
      for (int a = 0; a < 8; ++a) MFMA_A(acc[a], wA[a * 8 + ks], bf);
#pragma unroll
      for (int a = 8; a < 12; ++a) MFMA_V(acc[a], wV[(a - 8) * 8 + ks], bf);
      bf = bnx;
    }
    // raw-asm MFMA bypasses compiler hazard handling; drain the MFMA pipe
    // before VALU reads the accumulators.
    asm volatile("s_nop 7\n\ts_nop 7" :: );

    // ---- gate phase (all lanes compute; only col<4 lanes commit) ----
#pragma unroll
    for (int i = 0; i < 4; ++i) {
      h4 hold4 = *(const h4*)&hb[t & 1][fa_i[i]];
      f32x4v bn4 = *(const f32x4v*)&bnlds[u0 + 16 * i + 4 * g];
      f32x4v nh4, hn4;
#pragma unroll
      for (int r = 0; r < 4; ++r) {
        float hold = (float)hold4[r];
        float rr = sigf((float)gv[0][i][r] + acc[i][r]);
        float zz = sigf((float)gv[1][i][r] + acc[4 + i][r]);
        float nn = tanhf2((float)gv[2][i][r] + rr * (acc[8 + i][r] + bn4[r]));
        float nh = zz * (hold - nn) + nn;      // (1-z)n + z h
        nh4[r] = nh;
        hn4[r] = hold + mt * (nh - hold);      // mask blend
      }
      nhp[i] = nh4;
      if (act) {
        u32x2v hp;
        hp.x = pk2(hn4[0], hn4[1]);
        hp.y = pk2(hn4[2], hn4[3]);
        *(u32x2v*)&hb[(t + 1) & 1][fa_i[i]] = hp;
      }
    }
    __syncthreads();
  }

  if (act) {
#pragma unroll
    for (int i = 0; i < 4; ++i)
      *(f32x4v*)(outb + (size_t)(TT - 1) * HH + u0 + 16 * i + 4 * g) = nhp[i];
    // final state: h after step TT-1 lives in hb[TT&1] = hb[0]
#pragma unroll
    for (int i = 0; i < 4; ++i) {
      h4 hf = *(const h4*)&hb[0][fa_i[i]];
      f32x4v o;
#pragma unroll
      for (int r = 0; r < 4; ++r) o[r] = (float)hf[r];
      *(f32x4v*)(out + (size_t)BB * TT * HH + (size_t)bb * HH + u0 + 16 * i + 4 * g) = o;
    }
  }
}

extern "C" void kernel_launch(void* const* d_in, const int* in_sizes, int n_in,
                              void* d_out, int out_size, void* d_ws, size_t ws_size,
                              hipStream_t stream) {
  const float* x      = (const float*)d_in[0];
  const float* states = (const float*)d_in[1];
  const float* mask   = (const float*)d_in[2];
  const float* W_ih   = (const float*)d_in[3];
  const float* W_hh   = (const float*)d_in[4];
  const float* b_ih   = (const float*)d_in[5];
  const float* b_hh   = (const float*)d_in[6];
  float* out = (float*)d_out;

  char* ws = (char*)d_ws;
  f16* gi = (f16*)ws;
  u32* Wa = (u32*)(ws + GI_BYTES);

  prepack_wa<<<dim3(384), dim3(256), 0, stream>>>(W_hh, Wa);
  gemm_gi<<<dim3(512), dim3(256), 0, stream>>>(x, W_ih, b_ih, b_hh, gi);
  recur<<<dim3(16), dim3(256), 0, stream>>>(Wa, gi, states, mask, b_hh, out);
}

// Round 11
// 1378.906 us; speedup vs baseline: 3.7047x; 2.7970x over previous
//
#include <hip/hip_runtime.h>

typedef unsigned int u32;
typedef unsigned long long u64;
typedef __fp16 f16;
typedef __fp16 h2 __attribute__((ext_vector_type(2)));
typedef __fp16 h8 __attribute__((ext_vector_type(8)));
typedef float f32x2v __attribute__((ext_vector_type(2)));
typedef float f32x4v __attribute__((ext_vector_type(4)));
typedef float f32x16v __attribute__((ext_vector_type(16)));
typedef u32 u32x2v __attribute__((ext_vector_type(2)));
typedef u32 u32x4v __attribute__((ext_vector_type(4)));

static constexpr int BB = 64;     // batch
static constexpr int TT = 1024;   // seq len
static constexpr int HH = 256;    // hidden
static constexpr int GG = 768;    // 3*H
static constexpr size_t GI_BYTES = (size_t)BB * TT * GG * 2;  // f16 gi buffer

__device__ __forceinline__ u32 pk2(float a, float b) {
  h2 r = __builtin_amdgcn_cvt_pkrtz(a, b);
  return __builtin_bit_cast(u32, r);
}
__device__ __forceinline__ float dpp_x1(float x) {  // quad_perm [1,0,3,2]: pair swap
  return __builtin_bit_cast(float,
      __builtin_amdgcn_mov_dpp(__builtin_bit_cast(int, x), 0xB1, 0xF, 0xF, true));
}
__device__ __forceinline__ float sigf(float x) { return 1.f / (1.f + __expf(-x)); }
__device__ __forceinline__ float tanhf2(float x) {
  float e = __expf(2.f * x);
  return 1.f - 2.f / (e + 1.f);
}

// ---------------------------------------------------------------------------
// Phase 0: prepack W_hh (768x256 fp32) into per-THREAD CONTIGUOUS f16x2
// streams for the asm-core recur. Thread j (u=j>>1, kh=j&1) owns gate rows
// {u, 256+u, 512+u} over k-half [128kh,128kh+128). Dword idx = G*64+d of
// thread j = W_hh[G*256+u][128kh+2d .. +1], stored at Wp2[j*192 + idx] so the
// init asm does 48 global_load_dwordx4 from one base.
// ---------------------------------------------------------------------------
__global__ void prepack_whh(const float* __restrict__ Whh, u32* __restrict__ Wp2) {
  int id = blockIdx.x * 256 + threadIdx.x;  // [0, 512*192)
  int j = id / 192;
  int rem = id - j * 192;
  int G = rem >> 6, d = rem & 63;
  int u = j >> 1, kh = j & 1;
  const float* p = Whh + (size_t)(G * 256 + u) * HH + 128 * kh + 2 * d;
  Wp2[id] = pk2(p[0], p[1]);
}

// ---------------------------------------------------------------------------
// Phase 1: gi = x @ W_ih^T + b_ih (+ b_hh folded for r,z gates), stored f16.
// (unchanged, passed correctness)
// ---------------------------------------------------------------------------
__device__ __forceinline__ f32x16v zero16() {
  f32x16v z;
#pragma unroll
  for (int i = 0; i < 16; ++i) z[i] = 0.f;
  return z;
}

__global__ __launch_bounds__(256, 2) void gemm_gi(
    const float* __restrict__ x, const float* __restrict__ Wih,
    const float* __restrict__ bih, const float* __restrict__ bhh,
    f16* __restrict__ gi) {
  __shared__ u32 bl[16384];  // 128 rows x 128 dwords (f16x2) = 64KB
  const int tid = threadIdx.x;
  const int lane = tid & 63;
  const int wv = tid >> 6;
  const int wr = wv >> 1, wc = wv & 1;
  const int l31 = lane & 31, lh = lane >> 5;
  const int m0 = blockIdx.x << 7;

  u32x4v afr[2][16];
#pragma unroll
  for (int fr = 0; fr < 2; ++fr) {
#pragma unroll
    for (int km = 0; km < 16; ++km) {
      int row = m0 + wr * 64 + fr * 32 + l31;
      int k0 = km * 16 + lh * 8;
      const f32x4v* p = (const f32x4v*)(x + (size_t)row * 256 + k0);
      f32x4v u = p[0], v = p[1];
      u32x4v t;
      t.x = pk2(u.x, u.y); t.y = pk2(u.z, u.w);
      t.z = pk2(v.x, v.y); t.w = pk2(v.z, v.w);
      afr[fr][km] = t;
    }
  }

  for (int nt = 0; nt < 6; ++nt) {
    const int n0 = nt << 7;
#pragma unroll
    for (int it = 0; it < 32; ++it) {
      int flat = it * 256 + tid;
      int r = flat >> 6;
      int q = flat & 63;
      f32x4v f = *(const f32x4v*)(Wih + (size_t)(n0 + r) * 256 + 4 * q);
      u32x2v pw;
      pw.x = pk2(f.x, f.y);
      pw.y = pk2(f.z, f.w);
      int wd = 2 * q;
      *(u32x2v*)&bl[r * 128 + (wd ^ ((r & 15) << 2))] = pw;
    }
    __syncthreads();

    f32x16v acc00 = zero16(), acc01 = zero16(), acc10 = zero16(), acc11 = zero16();
#pragma unroll
    for (int km = 0; km < 16; ++km) {
      int w0 = km * 8 + lh * 4;
      int rc0 = wc * 64 + l31;
      int rc1 = wc * 64 + 32 + l31;
      u32x4v b0 = *(const u32x4v*)&bl[rc0 * 128 + (w0 ^ ((rc0 & 15) << 2))];
      u32x4v b1 = *(const u32x4v*)&bl[rc1 * 128 + (w0 ^ ((rc1 & 15) << 2))];
      h8 a0h = __builtin_bit_cast(h8, afr[0][km]);
      h8 a1h = __builtin_bit_cast(h8, afr[1][km]);
      h8 b0h = __builtin_bit_cast(h8, b0);
      h8 b1h = __builtin_bit_cast(h8, b1);
      acc00 = __builtin_amdgcn_mfma_f32_32x32x16_f16(a0h, b0h, acc00, 0, 0, 0);
      acc10 = __builtin_amdgcn_mfma_f32_32x32x16_f16(a1h, b0h, acc10, 0, 0, 0);
      acc01 = __builtin_amdgcn_mfma_f32_32x32x16_f16(a0h, b1h, acc01, 0, 0, 0);
      acc11 = __builtin_amdgcn_mfma_f32_32x32x16_f16(a1h, b1h, acc11, 0, 0, 0);
    }

#define EPI(ACC, FR, FC)                                                      \
    {                                                                         \
      int gc = n0 + wc * 64 + (FC) * 32 + l31;                                \
      float bias = bih[gc] + (gc < 512 ? bhh[gc] : 0.f);                      \
      _Pragma("unroll")                                                       \
      for (int rg = 0; rg < 16; ++rg) {                                       \
        int gr = m0 + wr * 64 + (FR) * 32 + 4 * lh + (rg & 3) + 8 * (rg >> 2);\
        gi[(size_t)gr * 768 + gc] = (f16)(ACC[rg] + bias);                    \
      }                                                                       \
    }
    EPI(acc00, 0, 0) EPI(acc10, 1, 0) EPI(acc01, 0, 1) EPI(acc11, 1, 1)
#undef EPI
    __syncthreads();
  }
}

// ---------------------------------------------------------------------------
// Phase 2: recurrence, asm-core.  Weights live in PHYSICAL v64..v255 (192
// dwords/thread), loaded once by an asm block and referenced as literal
// register names by 16 groups of 12 v_dot2_f32_f16 — regalloc cannot touch,
// spill, or copy them.  Every asm clobbers v64-v255 so C values stay in
// v0..v63.  64 blocks x 512 thr (8 waves, 2/SIMD at VGPR=256).  h f16 in LDS
// double-buffered, 1 barrier/step; gate math in C (r5-proven numerics).
// ---------------------------------------------------------------------------
#define WCLOB \
  "v64","v65","v66","v67","v68","v69","v70","v71", \
  "v72","v73","v74","v75","v76","v77","v78","v79", \
  "v80","v81","v82","v83","v84","v85","v86","v87", \
  "v88","v89","v90","v91","v92","v93","v94","v95", \
  "v96","v97","v98","v99","v100","v101","v102","v103", \
  "v104","v105","v106","v107","v108","v109","v110","v111", \
  "v112","v113","v114","v115","v116","v117","v118","v119", \
  "v120","v121","v122","v123","v124","v125","v126","v127", \
  "v128","v129","v130","v131","v132","v133","v134","v135", \
  "v136","v137","v138","v139","v140","v141","v142","v143", \
  "v144","v145","v146","v147","v148","v149","v150","v151", \
  "v152","v153","v154","v155","v156","v157","v158","v159", \
  "v160","v161","v162","v163","v164","v165","v166","v167", \
  "v168","v169","v170","v171","v172","v173","v174","v175", \
  "v176","v177","v178","v179","v180","v181","v182","v183", \
  "v184","v185","v186","v187","v188","v189","v190","v191", \
  "v192","v193","v194","v195","v196","v197","v198","v199", \
  "v200","v201","v202","v203","v204","v205","v206","v207", \
  "v208","v209","v210","v211","v212","v213","v214","v215", \
  "v216","v217","v218","v219","v220","v221","v222","v223", \
  "v224","v225","v226","v227","v228","v229","v230","v231", \
  "v232","v233","v234","v235","v236","v237","v238","v239", \
  "v240","v241","v242","v243","v244","v245","v246","v247", \
  "v248","v249","v250","v251","v252","v253","v254","v255"

#define LD16(A,B,OFF) "global_load_dwordx4 v[" #A ":" #B "], %0, off offset:" #OFF "\n\t"

#define DOTG(R0,R1,R2,R3,Z0,Z1,Z2,Z3,N0,N1,N2,N3,Q)          \
  asm volatile(                                              \
    "v_dot2_f32_f16 %0, v" #R0 ", %3, %0\n\t"                \
    "v_dot2_f32_f16 %1, v" #Z0 ", %3, %1\n\t"                \
    "v_dot2_f32_f16 %2, v" #N0 ", %3, %2\n\t"                \
    "v_dot2_f32_f16 %0, v" #R1 ", %4, %0\n\t"                \
    "v_dot2_f32_f16 %1, v" #Z1 ", %4, %1\n\t"                \
    "v_dot2_f32_f16 %2, v" #N1 ", %4, %2\n\t"                \
    "v_dot2_f32_f16 %0, v" #R2 ", %5, %0\n\t"                \
    "v_dot2_f32_f16 %1, v" #Z2 ", %5, %1\n\t"                \
    "v_dot2_f32_f16 %2, v" #N2 ", %5, %2\n\t"                \
    "v_dot2_f32_f16 %0, v" #R3 ", %6, %0\n\t"                \
    "v_dot2_f32_f16 %1, v" #Z3 ", %6, %1\n\t"                \
    "v_dot2_f32_f16 %2, v" #N3 ", %6, %2\n\t"                \
    : "+v"(ar), "+v"(az), "+v"(an)                           \
    : "v"((Q).x), "v"((Q).y), "v"((Q).z), "v"((Q).w)         \
    : WCLOB)

__global__ __launch_bounds__(512, 2) void recur(
    const u32* __restrict__ Wp2, const f16* __restrict__ gi,
    const float* __restrict__ states, const float* __restrict__ mask,
    const float* __restrict__ bhh_g, float* __restrict__ out) {
  const int b = blockIdx.x;
  const int j = threadIdx.x;
  const int u = j >> 1;
  const int kh = j & 1;

  __shared__ __align__(16) u32 hbuf[2][128];   // h as f16x2
  __shared__ float mlds[TT];                   // mask row, 4 KB

  const float bhn = bhh_g[512 + u];   // r,z biases folded into gi by gemm

  const float* mk = mask + b * TT;
  const f16* gcur = gi + (size_t)b * TT * GG + u;
  float* outb = out + (size_t)b * TT * HH;

  for (int i = j; i < TT; i += 512) mlds[i] = mk[i];

  float hreg = states[b * HH + u] * mk[0];   // both lanes of the pair
  if (kh == 0) ((f16*)hbuf[0])[u] = (f16)hreg;

  // ---- load 192 weight dwords into PHYSICAL v64..v255 (after all C staging) ----
  {
    u64 wa = (u64)(Wp2 + (size_t)j * 192);
    asm volatile(
      LD16(64,67,0)    LD16(68,71,16)   LD16(72,75,32)   LD16(76,79,48)
      LD16(80,83,64)   LD16(84,87,80)   LD16(88,91,96)   LD16(92,95,112)
      LD16(96,99,128)  LD16(100,103,144) LD16(104,107,160) LD16(108,111,176)
      LD16(112,115,192) LD16(116,119,208) LD16(120,123,224) LD16(124,127,240)
      LD16(128,131,256) LD16(132,135,272) LD16(136,139,288) LD16(140,143,304)
      LD16(144,147,320) LD16(148,151,336) LD16(152,155,352) LD16(156,159,368)
      LD16(160,163,384) LD16(164,167,400) LD16(168,171,416) LD16(172,175,432)
      LD16(176,179,448) LD16(180,183,464) LD16(184,187,480) LD16(188,191,496)
      LD16(192,195,512) LD16(196,199,528) LD16(200,203,544) LD16(204,207,560)
      LD16(208,211,576) LD16(212,215,592) LD16(216,219,608) LD16(220,223,624)
      LD16(224,227,640) LD16(228,231,656) LD16(232,235,672) LD16(236,239,688)
      LD16(240,243,704) LD16(244,247,720) LD16(248,251,736) LD16(252,255,752)
      "s_waitcnt vmcnt(0)\n\t"
      :: "v"(wa) : WCLOB, "memory");
  }
  __syncthreads();

  float nh_prev = 0.f;

  for (int t = 0; t < TT; ++t) {
    if (t > 0 && kh == 0) outb[(size_t)(t - 1) * HH + u] = nh_prev;
    f16 gr_c = gcur[0], gz_c = gcur[256], gn_c = gcur[512];
    const float mt = mlds[t];

    const u32x4v* hq = (const u32x4v*)&hbuf[t & 1][kh << 6];
    float ar = 0.f, az = 0.f, an = 0.f;

    { u32x4v q = hq[0];  DOTG(64,65,66,67,    128,129,130,131, 192,193,194,195, q); }
    { u32x4v q = hq[1];  DOTG(68,69,70,71,    132,133,134,135, 196,197,198,199, q); }
    { u32x4v q = hq[2];  DOTG(72,73,74,75,    136,137,138,139, 200,201,202,203, q); }
    { u32x4v q = hq[3];  DOTG(76,77,78,79,    140,141,142,143, 204,205,206,207, q); }
    { u32x4v q = hq[4];  DOTG(80,81,82,83,    144,145,146,147, 208,209,210,211, q); }
    { u32x4v q = hq[5];  DOTG(84,85,86,87,    148,149,150,151, 212,213,214,215, q); }
    { u32x4v q = hq[6];  DOTG(88,89,90,91,    152,153,154,155, 216,217,218,219, q); }
    { u32x4v q = hq[7];  DOTG(92,93,94,95,    156,157,158,159, 220,221,222,223, q); }
    { u32x4v q = hq[8];  DOTG(96,97,98,99,    160,161,162,163, 224,225,226,227, q); }
    { u32x4v q = hq[9];  DOTG(100,101,102,103, 164,165,166,167, 228,229,230,231, q); }
    { u32x4v q = hq[10]; DOTG(104,105,106,107, 168,169,170,171, 232,233,234,235, q); }
    { u32x4v q = hq[11]; DOTG(108,109,110,111, 172,173,174,175, 236,237,238,239, q); }
    { u32x4v q = hq[12]; DOTG(112,113,114,115, 176,177,178,179, 240,241,242,243, q); }
    { u32x4v q = hq[13]; DOTG(116,117,118,119, 180,181,182,183, 244,245,246,247, q); }
    { u32x4v q = hq[14]; DOTG(120,121,122,123, 184,185,186,187, 248,249,250,251, q); }
    { u32x4v q = hq[15]; DOTG(124,125,126,127, 188,189,190,191, 252,253,254,255, q); }

    // pair-reduce across the two k-halves (lane 2u <-> 2u+1)
    float ghr = ar + dpp_x1(ar);
    float ghz = az + dpp_x1(az);
    float ghn = an + dpp_x1(an);

    float r = sigf((float)gr_c + ghr);
    float z = sigf((float)gz_c + ghz);
    float n = tanhf2((float)gn_c + r * (ghn + bhn));
    float nh = z * (hreg - n) + n;            // (1-z)n + z h
    float hnew = hreg + mt * (nh - hreg);     // mask blend
    nh_prev = nh;
    hreg = hnew;
    if (kh == 0) ((f16*)hbuf[(t + 1) & 1])[u] = (f16)hnew;
    gcur += GG;
    __syncthreads();
  }

  if (kh == 0) {
    outb[(size_t)(TT - 1) * HH + u] = nh_prev;
    out[(size_t)BB * TT * HH + b * HH + u] = hreg;  // final state
  }
}

extern "C" void kernel_launch(void* const* d_in, const int* in_sizes, int n_in,
                              void* d_out, int out_size, void* d_ws, size_t ws_size,
                              hipStream_t stream) {
  const float* x      = (const float*)d_in[0];
  const float* states = (const float*)d_in[1];
  const float* mask   = (const float*)d_in[2];
  const float* W_ih   = (const float*)d_in[3];
  const float* W_hh   = (const float*)d_in[4];
  const float* b_ih   = (const float*)d_in[5];
  const float* b_hh   = (const float*)d_in[6];
  float* out = (float*)d_out;

  char* ws = (char*)d_ws;
  f16* gi = (f16*)ws;
  u32* Wp2 = (u32*)(ws + GI_BYTES);

  prepack_whh<<<dim3(384), dim3(256), 0, stream>>>(W_hh, Wp2);
  gemm_gi<<<dim3(512), dim3(256), 0, stream>>>(x, W_ih, b_ih, b_hh, gi);
  recur<<<dim3(64), dim3(512), 0, stream>>>(Wp2, gi, states, mask, b_hh, out);
}

// Round 12
// 1298.480 us; speedup vs baseline: 3.9342x; 1.0619x over previous
//
#include <hip/hip_runtime.h>

typedef unsigned int u32;
typedef unsigned long long u64;
typedef __fp16 f16;
typedef __fp16 h2 __attribute__((ext_vector_type(2)));
typedef __fp16 h8 __attribute__((ext_vector_type(8)));
typedef float f32x2v __attribute__((ext_vector_type(2)));
typedef float f32x4v __attribute__((ext_vector_type(4)));
typedef float f32x16v __attribute__((ext_vector_type(16)));
typedef u32 u32x2v __attribute__((ext_vector_type(2)));
typedef u32 u32x4v __attribute__((ext_vector_type(4)));

static constexpr int BB = 64;     // batch
static constexpr int TT = 1024;   // seq len
static constexpr int HH = 256;    // hidden
static constexpr int GG = 768;    // 3*H
static constexpr size_t GI_BYTES = (size_t)BB * TT * GG * 2;  // f16 gi buffer

__device__ __forceinline__ u32 pk2(float a, float b) {
  h2 r = __builtin_amdgcn_cvt_pkrtz(a, b);
  return __builtin_bit_cast(u32, r);
}
__device__ __forceinline__ float dpp_x1(float x) {  // quad_perm [1,0,3,2]: pair swap
  return __builtin_bit_cast(float,
      __builtin_amdgcn_mov_dpp(__builtin_bit_cast(int, x), 0xB1, 0xF, 0xF, true));
}
__device__ __forceinline__ float sigf(float x) { return 1.f / (1.f + __expf(-x)); }
__device__ __forceinline__ float tanhf2(float x) {
  float e = __expf(2.f * x);
  return 1.f - 2.f / (e + 1.f);
}

// ---------------------------------------------------------------------------
// Phase 0: prepack W_hh into per-THREAD CONTIGUOUS f16x2 streams (r11 layout,
// passed correctness).  Thread j (u=j>>1, kh=j&1) owns gate rows {u,256+u,
// 512+u} over k-half [128kh,128kh+128); dword G*64+d = W[G*256+u][128kh+2d..].
// ---------------------------------------------------------------------------
__global__ void prepack_whh(const float* __restrict__ Whh, u32* __restrict__ Wp2) {
  int id = blockIdx.x * 256 + threadIdx.x;  // [0, 512*192)
  int j = id / 192;
  int rem = id - j * 192;
  int G = rem >> 6, d = rem & 63;
  int u = j >> 1, kh = j & 1;
  const float* p = Whh + (size_t)(G * 256 + u) * HH + 128 * kh + 2 * d;
  Wp2[id] = pk2(p[0], p[1]);
}

// ---------------------------------------------------------------------------
// Phase 1: gi = x @ W_ih^T + b_ih (+ b_hh folded for r,z), f16. (unchanged)
// ---------------------------------------------------------------------------
__device__ __forceinline__ f32x16v zero16() {
  f32x16v z;
#pragma unroll
  for (int i = 0; i < 16; ++i) z[i] = 0.f;
  return z;
}

__global__ __launch_bounds__(256, 2) void gemm_gi(
    const float* __restrict__ x, const float* __restrict__ Wih,
    const float* __restrict__ bih, const float* __restrict__ bhh,
    f16* __restrict__ gi) {
  __shared__ u32 bl[16384];  // 128 rows x 128 dwords (f16x2) = 64KB
  const int tid = threadIdx.x;
  const int lane = tid & 63;
  const int wv = tid >> 6;
  const int wr = wv >> 1, wc = wv & 1;
  const int l31 = lane & 31, lh = lane >> 5;
  const int m0 = blockIdx.x << 7;

  u32x4v afr[2][16];
#pragma unroll
  for (int fr = 0; fr < 2; ++fr) {
#pragma unroll
    for (int km = 0; km < 16; ++km) {
      int row = m0 + wr * 64 + fr * 32 + l31;
      int k0 = km * 16 + lh * 8;
      const f32x4v* p = (const f32x4v*)(x + (size_t)row * 256 + k0);
      f32x4v u = p[0], v = p[1];
      u32x4v t;
      t.x = pk2(u.x, u.y); t.y = pk2(u.z, u.w);
      t.z = pk2(v.x, v.y); t.w = pk2(v.z, v.w);
      afr[fr][km] = t;
    }
  }

  for (int nt = 0; nt < 6; ++nt) {
    const int n0 = nt << 7;
#pragma unroll
    for (int it = 0; it < 32; ++it) {
      int flat = it * 256 + tid;
      int r = flat >> 6;
      int q = flat & 63;
      f32x4v f = *(const f32x4v*)(Wih + (size_t)(n0 + r) * 256 + 4 * q);
      u32x2v pw;
      pw.x = pk2(f.x, f.y);
      pw.y = pk2(f.z, f.w);
      int wd = 2 * q;
      *(u32x2v*)&bl[r * 128 + (wd ^ ((r & 15) << 2))] = pw;
    }
    __syncthreads();

    f32x16v acc00 = zero16(), acc01 = zero16(), acc10 = zero16(), acc11 = zero16();
#pragma unroll
    for (int km = 0; km < 16; ++km) {
      int w0 = km * 8 + lh * 4;
      int rc0 = wc * 64 + l31;
      int rc1 = wc * 64 + 32 + l31;
      u32x4v b0 = *(const u32x4v*)&bl[rc0 * 128 + (w0 ^ ((rc0 & 15) << 2))];
      u32x4v b1 = *(const u32x4v*)&bl[rc1 * 128 + (w0 ^ ((rc1 & 15) << 2))];
      h8 a0h = __builtin_bit_cast(h8, afr[0][km]);
      h8 a1h = __builtin_bit_cast(h8, afr[1][km]);
      h8 b0h = __builtin_bit_cast(h8, b0);
      h8 b1h = __builtin_bit_cast(h8, b1);
      acc00 = __builtin_amdgcn_mfma_f32_32x32x16_f16(a0h, b0h, acc00, 0, 0, 0);
      acc10 = __builtin_amdgcn_mfma_f32_32x32x16_f16(a1h, b0h, acc10, 0, 0, 0);
      acc01 = __builtin_amdgcn_mfma_f32_32x32x16_f16(a0h, b1h, acc01, 0, 0, 0);
      acc11 = __builtin_amdgcn_mfma_f32_32x32x16_f16(a1h, b1h, acc11, 0, 0, 0);
    }

#define EPI(ACC, FR, FC)                                                      \
    {                                                                         \
      int gc = n0 + wc * 64 + (FC) * 32 + l31;                                \
      float bias = bih[gc] + (gc < 512 ? bhh[gc] : 0.f);                      \
      _Pragma("unroll")                                                       \
      for (int rg = 0; rg < 16; ++rg) {                                       \
        int gr = m0 + wr * 64 + (FR) * 32 + 4 * lh + (rg & 3) + 8 * (rg >> 2);\
        gi[(size_t)gr * 768 + gc] = (f16)(ACC[rg] + bias);                    \
      }                                                                       \
    }
    EPI(acc00, 0, 0) EPI(acc10, 1, 0) EPI(acc01, 0, 1) EPI(acc11, 1, 1)
#undef EPI
    __syncthreads();
  }
}

// ---------------------------------------------------------------------------
// Phase 2: recurrence, asm-core v2.  Weights in PHYSICAL v64..v255 (r11
// loader).  The WHOLE dot phase is ONE asm block: 16 ds_read_b128 of h
// double-buffered through v[56:59]/v[60:63] with counted lgkmcnt(1) waits,
// interleaved with 192 v_dot2_f32_f16 naming weight regs literally.  C side
// keeps ~25 live regs in v0..v55 — no more per-group LDS latency exposure.
// 64 blocks x 512 thr (8 waves, 2/SIMD).  1 barrier/step.
// ---------------------------------------------------------------------------
#define WCLOB_LD \
  "v64","v65","v66","v67","v68","v69","v70","v71", \
  "v72","v73","v74","v75","v76","v77","v78","v79", \
  "v80","v81","v82","v83","v84","v85","v86","v87", \
  "v88","v89","v90","v91","v92","v93","v94","v95", \
  "v96","v97","v98","v99","v100","v101","v102","v103", \
  "v104","v105","v106","v107","v108","v109","v110","v111", \
  "v112","v113","v114","v115","v116","v117","v118","v119", \
  "v120","v121","v122","v123","v124","v125","v126","v127", \
  "v128","v129","v130","v131","v132","v133","v134","v135", \
  "v136","v137","v138","v139","v140","v141","v142","v143", \
  "v144","v145","v146","v147","v148","v149","v150","v151", \
  "v152","v153","v154","v155","v156","v157","v158","v159", \
  "v160","v161","v162","v163","v164","v165","v166","v167", \
  "v168","v169","v170","v171","v172","v173","v174","v175", \
  "v176","v177","v178","v179","v180","v181","v182","v183", \
  "v184","v185","v186","v187","v188","v189","v190","v191", \
  "v192","v193","v194","v195","v196","v197","v198","v199", \
  "v200","v201","v202","v203","v204","v205","v206","v207", \
  "v208","v209","v210","v211","v212","v213","v214","v215", \
  "v216","v217","v218","v219","v220","v221","v222","v223", \
  "v224","v225","v226","v227","v228","v229","v230","v231", \
  "v232","v233","v234","v235","v236","v237","v238","v239", \
  "v240","v241","v242","v243","v244","v245","v246","v247", \
  "v248","v249","v250","v251","v252","v253","v254","v255"

#define WCLOB "v56","v57","v58","v59","v60","v61","v62","v63", WCLOB_LD

#define LD16(A,B,OFF) "global_load_dwordx4 v[" #A ":" #B "], %0, off offset:" #OFF "\n\t"

#define RD_A(OFF) "ds_read_b128 v[56:59], %3 offset:" #OFF "\n\t"
#define RD_B(OFF) "ds_read_b128 v[60:63], %3 offset:" #OFF "\n\t"
#define WT1 "s_waitcnt lgkmcnt(1)\n\t"
#define WT0 "s_waitcnt lgkmcnt(0)\n\t"

#define GRP(Q0,Q1,Q2,Q3, R0,R1,R2,R3, Z0,Z1,Z2,Z3, N0,N1,N2,N3) \
  "v_dot2_f32_f16 %0, v" #R0 ", v" #Q0 ", %0\n\t" \
  "v_dot2_f32_f16 %1, v" #Z0 ", v" #Q0 ", %1\n\t" \
  "v_dot2_f32_f16 %2, v" #N0 ", v" #Q0 ", %2\n\t" \
  "v_dot2_f32_f16 %0, v" #R1 ", v" #Q1 ", %0\n\t" \
  "v_dot2_f32_f16 %1, v" #Z1 ", v" #Q1 ", %1\n\t" \
  "v_dot2_f32_f16 %2, v" #N1 ", v" #Q1 ", %2\n\t" \
  "v_dot2_f32_f16 %0, v" #R2 ", v" #Q2 ", %0\n\t" \
  "v_dot2_f32_f16 %1, v" #Z2 ", v" #Q2 ", %1\n\t" \
  "v_dot2_f32_f16 %2, v" #N2 ", v" #Q2 ", %2\n\t" \
  "v_dot2_f32_f16 %0, v" #R3 ", v" #Q3 ", %0\n\t" \
  "v_dot2_f32_f16 %1, v" #Z3 ", v" #Q3 ", %1\n\t" \
  "v_dot2_f32_f16 %2, v" #N3 ", v" #Q3 ", %2\n\t"

__global__ __launch_bounds__(512, 2) void recur(
    const u32* __restrict__ Wp2, const f16* __restrict__ gi,
    const float* __restrict__ states, const float* __restrict__ mask,
    const float* __restrict__ bhh_g, float* __restrict__ out) {
  const int b = blockIdx.x;
  const int j = threadIdx.x;
  const int u = j >> 1;
  const int kh = j & 1;

  __shared__ __align__(16) u32 hbuf[2][128];   // h as f16x2
  __shared__ float mlds[TT];                   // mask row, 4 KB

  const float bhn = bhh_g[512 + u];   // r,z biases folded into gi by gemm

  const float* mk = mask + b * TT;
  const f16* gcur = gi + (size_t)b * TT * GG + u;
  float* outb = out + (size_t)b * TT * HH;

  for (int i = j; i < TT; i += 512) mlds[i] = mk[i];

  float hreg = states[b * HH + u] * mk[0];   // both lanes of the pair
  if (kh == 0) ((f16*)hbuf[0])[u] = (f16)hreg;

  // ---- load 192 weight dwords into PHYSICAL v64..v255 ----
  {
    u64 wa = (u64)(Wp2 + (size_t)j * 192);
    asm volatile(
      LD16(64,67,0)    LD16(68,71,16)   LD16(72,75,32)   LD16(76,79,48)
      LD16(80,83,64)   LD16(84,87,80)   LD16(88,91,96)   LD16(92,95,112)
      LD16(96,99,128)  LD16(100,103,144) LD16(104,107,160) LD16(108,111,176)
      LD16(112,115,192) LD16(116,119,208) LD16(120,123,224) LD16(124,127,240)
      LD16(128,131,256) LD16(132,135,272) LD16(136,139,288) LD16(140,143,304)
      LD16(144,147,320) LD16(148,151,336) LD16(152,155,352) LD16(156,159,368)
      LD16(160,163,384) LD16(164,167,400) LD16(168,171,416) LD16(172,175,432)
      LD16(176,179,448) LD16(180,183,464) LD16(184,187,480) LD16(188,191,496)
      LD16(192,195,512) LD16(196,199,528) LD16(200,203,544) LD16(204,207,560)
      LD16(208,211,576) LD16(212,215,592) LD16(216,219,608) LD16(220,223,624)
      LD16(224,227,640) LD16(228,231,656) LD16(232,235,672) LD16(236,239,688)
      LD16(240,243,704) LD16(244,247,720) LD16(248,251,736) LD16(252,255,752)
      "s_waitcnt vmcnt(0)\n\t"
      :: "v"(wa) : WCLOB_LD, "memory");
  }
  __syncthreads();

  float nh_prev = 0.f;

  for (int t = 0; t < TT; ++t) {
    if (t > 0 && kh == 0) outb[(size_t)(t - 1) * HH + u] = nh_prev;
    f16 gr_c = gcur[0], gz_c = gcur[256], gn_c = gcur[512];

    u32 lds_addr = (u32)(size_t)(&hbuf[t & 1][kh << 6]);
    float ar = 0.f, az = 0.f, an = 0.f;

    asm volatile(
      WT0                      // drain any C-side DS ops so counting is exact
      RD_A(0) RD_B(16)
      WT1 GRP(56,57,58,59,  64,65,66,67,    128,129,130,131, 192,193,194,195) RD_A(32)
      WT1 GRP(60,61,62,63,  68,69,70,71,    132,133,134,135, 196,197,198,199) RD_B(48)
      WT1 GRP(56,57,58,59,  72,73,74,75,    136,137,138,139, 200,201,202,203) RD_A(64)
      WT1 GRP(60,61,62,63,  76,77,78,79,    140,141,142,143, 204,205,206,207) RD_B(80)
      WT1 GRP(56,57,58,59,  80,81,82,83,    144,145,146,147, 208,209,210,211) RD_A(96)
      WT1 GRP(60,61,62,63,  84,85,86,87,    148,149,150,151, 212,213,214,215) RD_B(112)
      WT1 GRP(56,57,58,59,  88,89,90,91,    152,153,154,155, 216,217,218,219) RD_A(128)
      WT1 GRP(60,61,62,63,  92,93,94,95,    156,157,158,159, 220,221,222,223) RD_B(144)
      WT1 GRP(56,57,58,59,  96,97,98,99,    160,161,162,163, 224,225,226,227) RD_A(160)
      WT1 GRP(60,61,62,63,  100,101,102,103, 164,165,166,167, 228,229,230,231) RD_B(176)
      WT1 GRP(56,57,58,59,  104,105,106,107, 168,169,170,171, 232,233,234,235) RD_A(192)
      WT1 GRP(60,61,62,63,  108,109,110,111, 172,173,174,175, 236,237,238,239) RD_B(208)
      WT1 GRP(56,57,58,59,  112,113,114,115, 176,177,178,179, 240,241,242,243) RD_A(224)
      WT1 GRP(60,61,62,63,  116,117,118,119, 180,181,182,183, 244,245,246,247) RD_B(240)
      WT1 GRP(56,57,58,59,  120,121,122,123, 184,185,186,187, 248,249,250,251)
      WT0 GRP(60,61,62,63,  124,125,126,127, 188,189,190,191, 252,253,254,255)
      : "+v"(ar), "+v"(az), "+v"(an)
      : "v"(lds_addr)
      : WCLOB, "memory");

    const float mt = mlds[t];

    // pair-reduce across the two k-halves (lane 2u <-> 2u+1)
    float ghr = ar + dpp_x1(ar);
    float ghz = az + dpp_x1(az);
    float ghn = an + dpp_x1(an);

    float r = sigf((float)gr_c + ghr);
    float z = sigf((float)gz_c + ghz);
    float n = tanhf2((float)gn_c + r * (ghn + bhn));
    float nh = z * (hreg - n) + n;            // (1-z)n + z h
    float hnew = hreg + mt * (nh - hreg);     // mask blend
    nh_prev = nh;
    hreg = hnew;
    if (kh == 0) ((f16*)hbuf[(t + 1) & 1])[u] = (f16)hnew;
    gcur += GG;
    __syncthreads();
  }

  if (kh == 0) {
    outb[(size_t)(TT - 1) * HH + u] = nh_prev;
    out[(size_t)BB * TT * HH + b * HH + u] = hreg;  // final state
  }
}

extern "C" void kernel_launch(void* const* d_in, const int* in_sizes, int n_in,
                              void* d_out, int out_size, void* d_ws, size_t ws_size,
                              hipStream_t stream) {
  const float* x      = (const float*)d_in[0];
  const float* states = (const float*)d_in[1];
  const float* mask   = (const float*)d_in[2];
  const float* W_ih   = (const float*)d_in[3];
  const float* W_hh   = (const float*)d_in[4];
  const float* b_ih   = (const float*)d_in[5];
  const float* b_hh   = (const float*)d_in[6];
  float* out = (float*)d_out;

  char* ws = (char*)d_ws;
  f16* gi = (f16*)ws;
  u32* Wp2 = (u32*)(ws + GI_BYTES);

  prepack_whh<<<dim3(384), dim3(256), 0, stream>>>(W_hh, Wp2);
  gemm_gi<<<dim3(512), dim3(256), 0, stream>>>(x, W_ih, b_ih, b_hh, gi);
  recur<<<dim3(64), dim3(512), 0, stream>>>(Wp2, gi, states, mask, b_hh, out);
}